// Round 3
// baseline (545.151 us; speedup 1.0000x reference)
//
#include <hip/hip_runtime.h>

// ---------------------------------------------------------------------------
// MoE top-1 (GShard) layer: gate -> capacity scan -> dispatch -> FFN(8 experts)
// -> combine.  n=4096 tokens, D=1024, E=8, F=4096, C=640.
// Strategy: bf16 MFMA (16x16x32) for both expert GEMMs; weights transposed +
// converted to bf16 in a pre-pass so both MFMA operands are k-inner.
// ---------------------------------------------------------------------------

#define NTOK 4096
#define DDIM 1024
#define EXP  8
#define FDIM 4096
#define CAP  640

typedef __attribute__((ext_vector_type(8))) __bf16 bf16x8;
typedef __attribute__((ext_vector_type(4))) float f32x4;

__device__ __forceinline__ unsigned short f2bf(float f) {
    unsigned int u = __float_as_uint(f);
    unsigned int r = (u + 0x7fffu + ((u >> 16) & 1u)) >> 16;   // RNE
    return (unsigned short)r;
}

__device__ __forceinline__ float gelu_tanh(float x) {
    float x3 = x * x * x;
    float t = tanhf(0.7978845608028654f * (x + 0.044715f * x3));
    return 0.5f * x * (1.0f + t);
}

__device__ __forceinline__ void gload16(const void* gsrc, void* ldst) {
    __builtin_amdgcn_global_load_lds((__attribute__((address_space(1))) void*)gsrc,
                                     (__attribute__((address_space(3))) void*)ldst,
                                     16, 0, 0);
}

// ---------------------------------------------------------------------------
// 0. zero-fill output (dropped tokens must be 0; harness poisons d_out)
__global__ void zero_kernel(float4* __restrict__ out, int n4) {
    int i = blockIdx.x * blockDim.x + threadIdx.x;
    if (i < n4) out[i] = make_float4(0.f, 0.f, 0.f, 0.f);
}

// ---------------------------------------------------------------------------
// 1. gate: logits -> softmax -> argmax.  One wave per token.
__global__ void gate_kernel(const float* __restrict__ tokens,
                            const float* __restrict__ gw,
                            const float* __restrict__ gb,
                            int* __restrict__ expert_idx,
                            float* __restrict__ gate_prob) {
    int wv = threadIdx.x >> 6, lane = threadIdx.x & 63;
    int t = blockIdx.x * 4 + wv;
    if (t >= NTOK) return;
    const float* tp = tokens + (size_t)t * DDIM;
    float acc[EXP];
#pragma unroll
    for (int e = 0; e < EXP; ++e) acc[e] = 0.f;
#pragma unroll
    for (int i = 0; i < DDIM / 64; ++i) {
        int d = i * 64 + lane;
        float x = tp[d];
        const float* g = gw + (size_t)d * EXP;
#pragma unroll
        for (int e = 0; e < EXP; ++e) acc[e] += x * g[e];
    }
#pragma unroll
    for (int e = 0; e < EXP; ++e) {
#pragma unroll
        for (int off = 32; off; off >>= 1) acc[e] += __shfl_xor(acc[e], off);
    }
    float lg[EXP];
#pragma unroll
    for (int e = 0; e < EXP; ++e) lg[e] = acc[e] + gb[e];
    int am = 0; float mx = lg[0];
#pragma unroll
    for (int e = 1; e < EXP; ++e) { if (lg[e] > mx) { mx = lg[e]; am = e; } }
    float s = 0.f;
#pragma unroll
    for (int e = 0; e < EXP; ++e) s += expf(lg[e] - mx);
    if (lane == 0) {
        expert_idx[t] = am;
        gate_prob[t] = 1.0f / s;     // exp(mx-mx)/s
    }
}

// ---------------------------------------------------------------------------
// 2. ordered capacity scan (single wave, replicates cumsum semantics exactly)
__global__ void scan_kernel(const int* __restrict__ expert_idx,
                            int* __restrict__ slot_token) {
    int lane = threadIdx.x;   // 64 threads
    for (int i = lane; i < EXP * CAP; i += 64) slot_token[i] = -1;
    int base[EXP];
#pragma unroll
    for (int e = 0; e < EXP; ++e) base[e] = 0;
    for (int c = 0; c < NTOK / 64; ++c) {
        int t = c * 64 + lane;
        int e = expert_idx[t];
        int pos = -1;
#pragma unroll
        for (int ex = 0; ex < EXP; ++ex) {
            unsigned long long m = __ballot(e == ex);
            if (e == ex) pos = base[ex] + __popcll(m & ((1ull << lane) - 1ull));
            base[ex] += __popcll(m);
        }
        if (pos < CAP) slot_token[e * CAP + pos] = t;
    }
}

// ---------------------------------------------------------------------------
// 3. dispatch gather: Xb[e][c][d] (bf16, k-inner) = tokens[slot] or 0
__global__ void dispatch_kernel(const float* __restrict__ tokens,
                                const int* __restrict__ slot_token,
                                unsigned short* __restrict__ Xb) {
    int s = blockIdx.x;                 // 0..E*CAP-1
    int tok = slot_token[s];
    int d = threadIdx.x * 4;
    ushort4 o;
    if (tok >= 0) {
        float4 v = *(const float4*)(tokens + (size_t)tok * DDIM + d);
        o.x = f2bf(v.x); o.y = f2bf(v.y); o.z = f2bf(v.z); o.w = f2bf(v.w);
    } else {
        o.x = o.y = o.z = o.w = 0;
    }
    *(ushort4*)(Xb + (size_t)s * DDIM + d) = o;
}

// ---------------------------------------------------------------------------
// 4. transpose+convert: w[e][R][Cc] f32 -> wt[e][Cc][R] bf16
__global__ void transpose_kernel(const float* __restrict__ w,
                                 unsigned short* __restrict__ wt,
                                 int R, int Cc) {
    __shared__ float tile[64][65];
    int e = blockIdx.z;
    int c0 = blockIdx.x * 64, r0 = blockIdx.y * 64;
    const float* wp = w + (size_t)e * R * Cc;
    unsigned short* op = wt + (size_t)e * R * Cc;
#pragma unroll
    for (int it = 0; it < 16; ++it) {
        int idx = it * 256 + threadIdx.x;
        int r = idx >> 6, c = idx & 63;
        tile[r][c] = wp[(size_t)(r0 + r) * Cc + (c0 + c)];
    }
    __syncthreads();
#pragma unroll
    for (int it = 0; it < 16; ++it) {
        int idx = it * 256 + threadIdx.x;
        int cc = idx >> 6, rr = idx & 63;
        op[(size_t)(c0 + cc) * R + (r0 + rr)] = f2bf(tile[rr][cc]);
    }
}

// ---------------------------------------------------------------------------
// 5. GEMM1: h[e][c][f] = gelu(Xb[e] @ w1t[e]^T + b1)   (M=640,N=4096,K=1024)
//    m97-style 128x128 tile, BK=32, 4 waves, 16x16x32 bf16 MFMA.
__global__ void gemm1_kernel(const unsigned short* __restrict__ Xb,
                             const unsigned short* __restrict__ w1t,
                             const float* __restrict__ b1,
                             unsigned short* __restrict__ h) {
    __shared__ __align__(16) unsigned short As[128 * 32];
    __shared__ __align__(16) unsigned short Bs[128 * 32];
    const int e = blockIdx.z;
    const int n0 = blockIdx.x * 128, m0 = blockIdx.y * 128;
    const int tid = threadIdx.x, lane = tid & 63, w = tid >> 6;
    const int wr = w >> 1, wc = w & 1;

    const int srow0 = tid >> 2;
    const int sk = (tid & 3) * 8;
    const unsigned short* a0 = Xb + ((size_t)(e * CAP + m0 + srow0) * DDIM + sk);
    const unsigned short* a1 = Xb + ((size_t)(e * CAP + m0 + srow0 + 64) * DDIM + sk);
    const unsigned short* b0 = w1t + ((size_t)(e * FDIM + n0 + srow0) * DDIM + sk);
    const unsigned short* b1v = w1t + ((size_t)(e * FDIM + n0 + srow0 + 64) * DDIM + sk);
    unsigned short* lA = As + (w << 9);
    unsigned short* lB = Bs + (w << 9);

    f32x4 acc[4][4] = {};
    const int rb = lane & 15, kq = (lane >> 4) * 8;
    for (int k0 = 0; k0 < DDIM; k0 += 32) {
        gload16(a0, lA); gload16(a1, lA + 2048);
        gload16(b0, lB); gload16(b1v, lB + 2048);
        __syncthreads();
        bf16x8 av[4], bv[4];
#pragma unroll
        for (int m = 0; m < 4; ++m)
            av[m] = *(const bf16x8*)(As + (wr * 64 + m * 16 + rb) * 32 + kq);
#pragma unroll
        for (int n = 0; n < 4; ++n)
            bv[n] = *(const bf16x8*)(Bs + (wc * 64 + n * 16 + rb) * 32 + kq);
#pragma unroll
        for (int m = 0; m < 4; ++m)
#pragma unroll
            for (int n = 0; n < 4; ++n)
                acc[m][n] = __builtin_amdgcn_mfma_f32_16x16x32_bf16(av[m], bv[n], acc[m][n], 0, 0, 0);
        __syncthreads();
        a0 += 32; a1 += 32; b0 += 32; b1v += 32;
    }
    // epilogue: +b1, gelu, store bf16
#pragma unroll
    for (int n = 0; n < 4; ++n) {
        int col = n0 + wc * 64 + n * 16 + rb;
        float bias = b1[e * FDIM + col];
#pragma unroll
        for (int m = 0; m < 4; ++m) {
            int rowb = m0 + wr * 64 + m * 16 + ((lane >> 4) << 2);
#pragma unroll
            for (int r = 0; r < 4; ++r) {
                float x = acc[m][n][r] + bias;
                h[(size_t)(e * CAP + rowb + r) * FDIM + col] = f2bf(gelu_tanh(x));
            }
        }
    }
}

// ---------------------------------------------------------------------------
// 6. GEMM2 + combine scatter: out[tok] = gp * (h[e] @ w2t[e]^T + b2)
//    (M=640, N=1024, K=4096)
__global__ void gemm2_kernel(const unsigned short* __restrict__ h,
                             const unsigned short* __restrict__ w2t,
                             const float* __restrict__ b2,
                             const int* __restrict__ slot_token,
                             const float* __restrict__ gate_prob,
                             float* __restrict__ out) {
    __shared__ __align__(16) unsigned short As[128 * 32];
    __shared__ __align__(16) unsigned short Bs[128 * 32];
    const int e = blockIdx.z;
    const int n0 = blockIdx.x * 128, m0 = blockIdx.y * 128;
    const int tid = threadIdx.x, lane = tid & 63, w = tid >> 6;
    const int wr = w >> 1, wc = w & 1;

    const int srow0 = tid >> 2;
    const int sk = (tid & 3) * 8;
    const unsigned short* a0 = h + ((size_t)(e * CAP + m0 + srow0) * FDIM + sk);
    const unsigned short* a1 = h + ((size_t)(e * CAP + m0 + srow0 + 64) * FDIM + sk);
    const unsigned short* b0 = w2t + ((size_t)(e * DDIM + n0 + srow0) * FDIM + sk);
    const unsigned short* b1v = w2t + ((size_t)(e * DDIM + n0 + srow0 + 64) * FDIM + sk);
    unsigned short* lA = As + (w << 9);
    unsigned short* lB = Bs + (w << 9);

    f32x4 acc[4][4] = {};
    const int rb = lane & 15, kq = (lane >> 4) * 8;
    for (int k0 = 0; k0 < FDIM; k0 += 32) {
        gload16(a0, lA); gload16(a1, lA + 2048);
        gload16(b0, lB); gload16(b1v, lB + 2048);
        __syncthreads();
        bf16x8 av[4], bv[4];
#pragma unroll
        for (int m = 0; m < 4; ++m)
            av[m] = *(const bf16x8*)(As + (wr * 64 + m * 16 + rb) * 32 + kq);
#pragma unroll
        for (int n = 0; n < 4; ++n)
            bv[n] = *(const bf16x8*)(Bs + (wc * 64 + n * 16 + rb) * 32 + kq);
#pragma unroll
        for (int m = 0; m < 4; ++m)
#pragma unroll
            for (int n = 0; n < 4; ++n)
                acc[m][n] = __builtin_amdgcn_mfma_f32_16x16x32_bf16(av[m], bv[n], acc[m][n], 0, 0, 0);
        __syncthreads();
        a0 += 32; a1 += 32; b0 += 32; b1v += 32;
    }
    // epilogue: +b2, gate scale, scatter to out rows
#pragma unroll
    for (int m = 0; m < 4; ++m) {
        int rowb = m0 + wr * 64 + m * 16 + ((lane >> 4) << 2);
#pragma unroll
        for (int r = 0; r < 4; ++r) {
            int slot = e * CAP + rowb + r;
            int tok = slot_token[slot];
            if (tok < 0) continue;
            float gp = gate_prob[tok];
#pragma unroll
            for (int n = 0; n < 4; ++n) {
                int col = n0 + wc * 64 + n * 16 + rb;
                out[(size_t)tok * DDIM + col] = gp * (acc[m][n][r] + b2[e * DDIM + col]);
            }
        }
    }
}

// ---------------------------------------------------------------------------
extern "C" void kernel_launch(void* const* d_in, const int* in_sizes, int n_in,
                              void* d_out, int out_size, void* d_ws, size_t ws_size,
                              hipStream_t stream) {
    const float* inputs = (const float*)d_in[0];
    const float* gate_w = (const float*)d_in[1];
    const float* gate_b = (const float*)d_in[2];
    const float* w1     = (const float*)d_in[3];
    const float* b1     = (const float*)d_in[4];
    const float* w2     = (const float*)d_in[5];
    const float* b2     = (const float*)d_in[6];
    float* out = (float*)d_out;

    char* ws = (char*)d_ws;
    int*   slot_token = (int*)ws;                                   // 20480 B
    int*   expert_idx = (int*)(ws + 20480);                         // 16384 B
    float* gate_prob  = (float*)(ws + 36864);                       // 16384 B
    unsigned short* Xb  = (unsigned short*)(ws + 53248);            // 10.5 MB
    unsigned short* w1t = (unsigned short*)(ws + 53248 + 10485760);  // 67 MB
    unsigned short* w2t = (unsigned short*)(ws + 53248 + 10485760 + 67108864);
    unsigned short* h   = (unsigned short*)(ws + 53248 + 10485760 + 2ull * 67108864);
    // total ws need: ~187 MiB

    zero_kernel<<<4096, 256, 0, stream>>>((float4*)out, NTOK * DDIM / 4);
    gate_kernel<<<NTOK / 4, 256, 0, stream>>>(inputs, gate_w, gate_b, expert_idx, gate_prob);
    scan_kernel<<<1, 64, 0, stream>>>(expert_idx, slot_token);
    dispatch_kernel<<<EXP * CAP, 256, 0, stream>>>(inputs, slot_token, Xb);
    transpose_kernel<<<dim3(FDIM / 64, DDIM / 64, EXP), 256, 0, stream>>>(w1, w1t, DDIM, FDIM);
    transpose_kernel<<<dim3(DDIM / 64, FDIM / 64, EXP), 256, 0, stream>>>(w2, w2t, FDIM, DDIM);
    gemm1_kernel<<<dim3(FDIM / 128, CAP / 128, EXP), 256, 0, stream>>>(Xb, w1t, b1, h);
    gemm2_kernel<<<dim3(DDIM / 128, CAP / 128, EXP), 256, 0, stream>>>(h, w2t, b2, slot_token, gate_prob, out);
}